// Round 3
// baseline (7376.492 us; speedup 1.0000x reference)
//
#include <hip/hip_runtime.h>

// ---------------- types / helpers ----------------
typedef unsigned short u16;
typedef __bf16 bf16x8 __attribute__((ext_vector_type(8)));
typedef float f32x4 __attribute__((ext_vector_type(4)));
typedef float f32x2 __attribute__((ext_vector_type(2)));
typedef u16 u16x8 __attribute__((ext_vector_type(8)));

static_assert(sizeof(bf16x8) == 16, "bf16x8 must be 16B");

#define DEV static __device__ __forceinline__

DEV u16 f2bf(float f) {
  unsigned u = __float_as_uint(f);
  u += 0x7FFFu + ((u >> 16) & 1u);  // RNE
  return (u16)(u >> 16);
}
DEV float bf2f(u16 h) { return __uint_as_float(((unsigned)h) << 16); }
DEV f32x4 mfma16(bf16x8 a, bf16x8 b, f32x4 c) {
  return __builtin_amdgcn_mfma_f32_16x16x32_bf16(a, b, c, 0, 0, 0);
}
DEV bf16x8 ldfrag(const u16* p) { return *reinterpret_cast<const bf16x8*>(p); }
DEV float sigf(float x) { return 1.0f / (1.0f + __expf(-x)); }
DEV bf16x8 asbf(f32x4 v) { union { f32x4 f; bf16x8 h; } u; u.f = v; return u.h; }
DEV void gld16(const void* g, void* l) {
  __builtin_amdgcn_global_load_lds((const __attribute__((address_space(1))) void*)g,
                                   (__attribute__((address_space(3))) void*)l, 16, 0, 0);
}

// ---- coherent (MALL-level, cross-XCD) access helpers: all comm data uses these ----
DEV void ld_a8_coh(const void* p, f32x4& o0, f32x4& o1, f32x4& o2, f32x4& o3, f32x4& o4,
                   f32x4& o5, f32x4& o6, f32x4& o7) {
  asm volatile(
      "global_load_dwordx4 %0, %8, off sc0 sc1\n\t"
      "global_load_dwordx4 %1, %8, off offset:64 sc0 sc1\n\t"
      "global_load_dwordx4 %2, %8, off offset:128 sc0 sc1\n\t"
      "global_load_dwordx4 %3, %8, off offset:192 sc0 sc1\n\t"
      "global_load_dwordx4 %4, %8, off offset:256 sc0 sc1\n\t"
      "global_load_dwordx4 %5, %8, off offset:320 sc0 sc1\n\t"
      "global_load_dwordx4 %6, %8, off offset:384 sc0 sc1\n\t"
      "global_load_dwordx4 %7, %8, off offset:448 sc0 sc1\n\t"
      "s_waitcnt vmcnt(0)"
      : "=&v"(o0), "=&v"(o1), "=&v"(o2), "=&v"(o3), "=&v"(o4), "=&v"(o5), "=&v"(o6), "=&v"(o7)
      : "v"(p)
      : "memory");
}
DEV void ld32_coh(const void* p, f32x4& a, f32x4& b) {
  asm volatile(
      "global_load_dwordx4 %0, %2, off sc0 sc1\n\t"
      "global_load_dwordx4 %1, %2, off offset:16 sc0 sc1\n\t"
      "s_waitcnt vmcnt(0)"
      : "=&v"(a), "=&v"(b)
      : "v"(p)
      : "memory");
}
DEV f32x2 ld8_coh(const void* p) {
  f32x2 r;
  asm volatile("global_load_dwordx2 %0, %1, off sc0 sc1\n\ts_waitcnt vmcnt(0)"
               : "=&v"(r) : "v"(p) : "memory");
  return r;
}
DEV void st32_coh(void* p, unsigned v) {
  asm volatile("global_store_dword %0, %1, off sc0 sc1" ::"v"(p), "v"(v) : "memory");
}
DEV void st_f32_coh(void* p, float v) {
  asm volatile("global_store_dword %0, %1, off sc0 sc1" ::"v"(p), "v"(v) : "memory");
}

// ---- grid barrier: monotonic counter, relaxed agent atomics, no cache fences ----
#define NBLK 256
DEV void gbar(unsigned* cnt, unsigned target) {
  asm volatile("s_waitcnt vmcnt(0)" ::: "memory");
  __syncthreads();
  if (threadIdx.x == 0) {
    __hip_atomic_fetch_add(cnt, 1u, __ATOMIC_RELAXED, __HIP_MEMORY_SCOPE_AGENT);
    while (__hip_atomic_load(cnt, __ATOMIC_RELAXED, __HIP_MEMORY_SCOPE_AGENT) < target)
      __builtin_amdgcn_s_sleep(2);
  }
  __syncthreads();
}
DEV void wave_wait(unsigned* cnt, unsigned target) {
  while (__hip_atomic_load(cnt, __ATOMIC_RELAXED, __HIP_MEMORY_SCOPE_AGENT) < target)
    __builtin_amdgcn_s_sleep(2);
}

// dims
#define Bn 32
#define Sn 128
#define Td 127
#define En 512
#define Hn 1024
#define G4 4096
#define Vn 32000

// ---------------- f32 -> bf16 convert ----------------
__global__ __launch_bounds__(256) void cvt_bf16_kernel(const float* __restrict__ in,
                                                       u16* __restrict__ out, int n8) {
  int gid = blockIdx.x * 256 + threadIdx.x;
  if (gid >= n8) return;
  const float4* ip = (const float4*)in + gid * 2;
  float4 x = ip[0], y = ip[1];
  u16x8 o;
  o[0] = f2bf(x.x); o[1] = f2bf(x.y); o[2] = f2bf(x.z); o[3] = f2bf(x.w);
  o[4] = f2bf(y.x); o[5] = f2bf(y.y); o[6] = f2bf(y.z); o[7] = f2bf(y.w);
  ((u16x8*)out)[gid] = o;
}

// ---------------- embedding gather ----------------
__global__ __launch_bounds__(256) void gather_embed_kernel(const int* __restrict__ idx, int ldidx,
                                                           const float* __restrict__ embed,
                                                           u16* __restrict__ outA, int nrows) {
  int gid = blockIdx.x * 256 + threadIdx.x;
  int total = nrows * (En / 8);
  if (gid >= total) return;
  int r = gid / (En / 8);
  int ck = gid % (En / 8);
  int tcol = r / Bn, b = r % Bn;
  int tok = idx[b * ldidx + tcol];
  const float4* src = (const float4*)(embed + (size_t)tok * En + ck * 8);
  float4 x = src[0], y = src[1];
  u16x8 o;
  o[0] = f2bf(x.x); o[1] = f2bf(x.y); o[2] = f2bf(x.z); o[3] = f2bf(x.w);
  o[4] = f2bf(y.x); o[5] = f2bf(y.y); o[6] = f2bf(y.z); o[7] = f2bf(y.w);
  *(u16x8*)(outA + (size_t)r * En + ck * 8) = o;
}

// ---------------- tiled GEMM (128x128, BK=32, global_load_lds) ----------------
__global__ __launch_bounds__(256) void gemm_tile_kernel(const u16* __restrict__ A, int lda,
                                                        const u16* __restrict__ W, int ldw,
                                                        const float* __restrict__ bias0,
                                                        const float* __restrict__ bias1,
                                                        float* __restrict__ Cout, int ldc,
                                                        int Mtiles, int K, int mode) {
  __shared__ u16 Asb[128 * 32];
  __shared__ u16 Bsb[128 * 32];
  int nwg = gridDim.x;
  int cpx = nwg >> 3;
  int bid = ((int)blockIdx.x & 7) * cpx + ((int)blockIdx.x >> 3);
  int mt = bid % Mtiles, nt = bid / Mtiles;
  int tid = threadIdx.x;
  int wave = tid >> 6, lane = tid & 63;
  int lrow = lane & 15, kgrp = lane >> 4;
  int wr = wave >> 1, wc = wave & 1;
  int e0 = wave * 1024 + lane * 8;
  int r0 = e0 >> 5, c0 = e0 & 31;
  int r1 = r0 + 16;
  const u16* Ab = A + (size_t)(mt * 128) * lda;
  const u16* Wb = W + (size_t)(nt * 128) * ldw;
  u16* AsW = Asb + wave * 1024;
  u16* BsW = Bsb + wave * 1024;
  f32x4 acc[4][4] = {};
  for (int k0 = 0; k0 < K; k0 += 32) {
    gld16(Ab + (size_t)r0 * lda + k0 + c0, AsW);
    gld16(Ab + (size_t)r1 * lda + k0 + c0, AsW + 512);
    gld16(Wb + (size_t)r0 * ldw + k0 + c0, BsW);
    gld16(Wb + (size_t)r1 * ldw + k0 + c0, BsW + 512);
    __syncthreads();
    bf16x8 af[4], bfr[4];
#pragma unroll
    for (int i = 0; i < 4; ++i) af[i] = ldfrag(Asb + (wr * 64 + i * 16 + lrow) * 32 + kgrp * 8);
#pragma unroll
    for (int i = 0; i < 4; ++i) bfr[i] = ldfrag(Bsb + (wc * 64 + i * 16 + lrow) * 32 + kgrp * 8);
#pragma unroll
    for (int i = 0; i < 4; ++i)
#pragma unroll
      for (int j = 0; j < 4; ++j) acc[i][j] = mfma16(af[i], bfr[j], acc[i][j]);
    __syncthreads();
  }
  if (mode == 0) {
#pragma unroll
    for (int i = 0; i < 4; ++i) {
      int m = mt * 128 + wr * 64 + i * 16 + kgrp * 4;
#pragma unroll
      for (int j = 0; j < 4; ++j) {
        int n = nt * 128 + wc * 64 + j * 16 + lrow;
        float bb = (bias0 ? bias0[n] : 0.f) + (bias1 ? bias1[n] : 0.f);
#pragma unroll
        for (int r = 0; r < 4; ++r) Cout[(size_t)(m + r) * ldc + n] = acc[i][j][r] + bb;
      }
    }
  } else {
#pragma unroll
    for (int i = 0; i < 4; ++i) {
      int m = mt * 128 + wr * 64 + i * 16 + kgrp * 4;
#pragma unroll
      for (int j = 0; j < 4; ++j) {
        int n = nt * 128 + wc * 64 + j * 16 + lrow;
        float bb = bias0[n];
#pragma unroll
        for (int r = 0; r < 4; ++r) {
          int mm = m + r;
          if (mm < Td * Bn) {
            int tt = mm >> 5, b = mm & 31;
            Cout[((size_t)b * Td + tt) * Vn + n] = acc[i][j][r] + bb;
          }
        }
      }
    }
  }
}

// ---------------- persistent-kernel building blocks ----------------
// 4-wave K-split 16x16x4gates GEMM; A read coherent (sc1), W read plain (L2-pinned).
DEV void gemm4_coh(const u16* __restrict__ A, const u16* __restrict__ Wrow, size_t gstride,
                   int arow, int wave, int kgrp, f32x4 acc[4]) {
  f32x4 t0, t1, t2, t3, t4, t5, t6, t7;
  ld_a8_coh(A + (size_t)arow * Hn + wave * 256 + kgrp * 8, t0, t1, t2, t3, t4, t5, t6, t7);
#define K_STEP(AF, KOFF)                                              \
  {                                                                   \
    bf16x8 aF = asbf(AF);                                             \
    _Pragma("unroll") for (int g = 0; g < 4; ++g) {                   \
      bf16x8 bF = ldfrag(Wrow + (size_t)g * gstride + KOFF);          \
      acc[g] = mfma16(aF, bF, acc[g]);                                \
    }                                                                 \
  }
  K_STEP(t0, 0) K_STEP(t1, 32) K_STEP(t2, 64) K_STEP(t3, 96)
  K_STEP(t4, 128) K_STEP(t5, 160) K_STEP(t6, 192) K_STEP(t7, 224)
#undef K_STEP
}

// cross-wave reduce + LSTM activations; c kept in a register. Returns h_new.
DEV float lstm_reduce_act(float lds[4][4][16][16], f32x4 acc[4], int wave, int lrow, int kgrp,
                          int tid, const float gadd[4], float* c_reg) {
#pragma unroll
  for (int g = 0; g < 4; ++g)
#pragma unroll
    for (int r = 0; r < 4; ++r) lds[wave][g][kgrp * 4 + r][lrow] = acc[g][r];
  __syncthreads();
  int row = tid >> 4, col = tid & 15;
  float gs[4];
#pragma unroll
  for (int g = 0; g < 4; ++g)
    gs[g] = lds[0][g][row][col] + lds[1][g][row][col] + lds[2][g][row][col] +
            lds[3][g][row][col] + gadd[g];
  float ig = sigf(gs[0]), fg = sigf(gs[1]), gg = tanhf(gs[2]), og = sigf(gs[3]);
  float cn = fg * (*c_reg) + ig * gg;
  *c_reg = cn;
  return og * tanhf(cn);
}

// ---------------- persistent encoder: 129 iterations, layer0(t) || layer1(t-1) ----------------
__global__ __launch_bounds__(256, 1) void enc_persist_kernel(
    const float* __restrict__ premix, const u16* __restrict__ Whh0, const u16* __restrict__ Wih1,
    const u16* __restrict__ Whh1, const float* __restrict__ bih1, const float* __restrict__ bhh1,
    u16* __restrict__ h0buf, u16* __restrict__ h1buf, float* __restrict__ c1_out,
    u16* __restrict__ enc_b, unsigned* __restrict__ barcnt) {
  __shared__ float lds[4][4][16][16];
  const int tid = threadIdx.x;
  const int wave = tid >> 6, lane = tid & 63;
  const int lrow = lane & 15, kgrp = lane >> 4;
  const int blk = blockIdx.x;
  const bool l1 = blk >= 128;
  const int idx = blk & 127;
  const int mt = (idx >> 3) & 1;                      // blocks 8 apart share ht -> L2 dedup
  const int ht = (idx & 7) | ((idx >> 4) << 3);
  const int row = tid >> 4, col = tid & 15;
  const int brow = mt * 16 + row, hcol = ht * 16 + col;
  const size_t hoff = (size_t)brow * Hn + hcol;
  const int arow = mt * 16 + lrow;
  const size_t wro = (size_t)(ht * 16 + lrow);
  const u16* w0r = Whh0 + wro * 1024 + wave * 256 + kgrp * 8;
  const u16* wi1r = Wih1 + wro * 1024 + wave * 256 + kgrp * 8;
  const u16* wh1r = Whh1 + wro * 1024 + wave * 256 + kgrp * 8;
  float c_reg = 0.f;
  float badd[4];
  if (l1) {
#pragma unroll
    for (int g = 0; g < 4; ++g) badd[g] = bih1[g * Hn + hcol] + bhh1[g * Hn + hcol];
  }
  unsigned bar = 0;
  for (int t = 0; t <= Sn; ++t) {
    if (!l1) {
      if (t < Sn) {
        const u16* hin = h0buf + (size_t)(t & 1) * Bn * Hn;
        u16* hout = h0buf + (size_t)((t + 1) & 1) * Bn * Hn;
        const float* pmr = premix + (size_t)t * Bn * G4 + (size_t)brow * G4 + hcol;
        float pm[4];
#pragma unroll
        for (int g = 0; g < 4; ++g) pm[g] = pmr[(size_t)g * Hn];
        f32x4 acc[4] = {};
        gemm4_coh(hin, w0r, (size_t)Hn * 1024, arow, wave, kgrp, acc);
        float hn = lstm_reduce_act(lds, acc, wave, lrow, kgrp, tid, pm, &c_reg);
        u16 mine = f2bf(hn);
        unsigned nb = (unsigned)(u16)__shfl_xor((int)mine, 1);
        if (!(tid & 1)) st32_coh(hout + hoff, ((unsigned)mine) | (nb << 16));
      }
    } else {
      if (t >= 1) {
        const u16* h0r = h0buf + (size_t)(t & 1) * Bn * Hn;        // h0(t-1)
        const u16* h1r = h1buf + (size_t)((t + 1) & 1) * Bn * Hn;  // h1(t-2)
        u16* h1w = h1buf + (size_t)(t & 1) * Bn * Hn;
        f32x4 acc[4] = {};
        gemm4_coh(h0r, wi1r, (size_t)Hn * 1024, arow, wave, kgrp, acc);
        gemm4_coh(h1r, wh1r, (size_t)Hn * 1024, arow, wave, kgrp, acc);
        float hn = lstm_reduce_act(lds, acc, wave, lrow, kgrp, tid, badd, &c_reg);
        u16 mine = f2bf(hn);
        unsigned nb = (unsigned)(u16)__shfl_xor((int)mine, 1);
        unsigned packed = ((unsigned)mine) | (nb << 16);
        if (!(tid & 1)) {
          st32_coh(h1w + hoff, packed);
          *(unsigned*)(enc_b + (size_t)(t - 1) * Bn * Hn + hoff) = packed;  // plain: next kernel
        }
        if (t == Sn) c1_out[hoff] = c_reg;
      }
    }
    gbar(barcnt, (++bar) * NBLK);
  }
}

// ---------------- persistent decoder: 127 iterations of {scores||h-GEMM, ctx, step} -------------
__global__ __launch_bounds__(256, 1) void dec_persist_kernel(
    const float* __restrict__ premix, const u16* __restrict__ Wctx, const u16* __restrict__ Whh,
    const float* __restrict__ c_init, u16* __restrict__ hbuf, const u16* __restrict__ enc_b,
    float* __restrict__ scores, u16* __restrict__ ctxb, u16* __restrict__ hs_dec,
    unsigned* __restrict__ barcnt, unsigned* __restrict__ cfine) {
  __shared__ float lds[4][4][16][16];
  __shared__ float wsm[Sn];
  const int tid = threadIdx.x;
  const int wave = tid >> 6, lane = tid & 63;
  const int lrow = lane & 15, kgrp = lane >> 4;
  const int blk = blockIdx.x;
  unsigned bar = 0;
  if (blk < 128) {
    // ---- step-GEMM role ----
    const int mt = (blk >> 3) & 1;
    const int ht = (blk & 7) | ((blk >> 4) << 3);
    const int row = tid >> 4, col = tid & 15;
    const int brow = mt * 16 + row, hcol = ht * 16 + col;
    const size_t hoff = (size_t)brow * Hn + hcol;
    const int arow = mt * 16 + lrow;
    const u16* wH = Whh + (size_t)(ht * 16 + lrow) * 1024 + wave * 256 + kgrp * 8;
    const u16* wC = Wctx + (size_t)(ht * 16 + lrow) * 1536 + wave * 256 + kgrp * 8;
    float c_reg = c_init[hoff];
    for (int t = 0; t < Td; ++t) {
      f32x4 acc[4] = {};
      gemm4_coh(hbuf, wH, (size_t)Hn * 1024, arow, wave, kgrp, acc);  // h(t) @ Whh^T
      gbar(barcnt, (++bar) * NBLK);                                   // X end
      const float* pmr = premix + (size_t)t * Bn * G4 + (size_t)brow * G4 + hcol;
      float pm[4];
#pragma unroll
      for (int g = 0; g < 4; ++g) pm[g] = pmr[(size_t)g * Hn];
      wave_wait(cfine + (mt * 4 + wave) * 32, 16u * (unsigned)(t + 1));  // ctx quarter ready
      gemm4_coh(ctxb, wC, (size_t)Hn * 1536, arow, wave, kgrp, acc);     // ctx(t) @ Wctx^T
      float hn = lstm_reduce_act(lds, acc, wave, lrow, kgrp, tid, pm, &c_reg);
      u16 mine = f2bf(hn);
      unsigned nb = (unsigned)(u16)__shfl_xor((int)mine, 1);
      unsigned packed = ((unsigned)mine) | (nb << 16);
      if (!(tid & 1)) {
        st32_coh(hbuf + hoff, packed);                                // publish h(t+1)
        *(unsigned*)(hs_dec + (size_t)t * Bn * Hn + hoff) = packed;   // plain: fc kernel
      }
      gbar(barcnt, (++bar) * NBLK);                                   // Z end
    }
  } else {
    // ---- attention role: (b, q) ----
    const int up = blk - 128;
    const int b = up >> 2, q = up & 3;
    const u16* hrow = hbuf + (size_t)b * Hn + lane * 16;
    for (int t = 0; t < Td; ++t) {
      // phase X: scores for s = q*32 + wave*8 + i
      union { f32x4 f; u16 u[8]; } U0, U1;
      ld32_coh(hrow, U0.f, U1.f);
      float hf[16];
#pragma unroll
      for (int i = 0; i < 8; ++i) { hf[i] = bf2f(U0.u[i]); hf[8 + i] = bf2f(U1.u[i]); }
#pragma unroll
      for (int i = 0; i < 8; ++i) {
        int s = q * 32 + wave * 8 + i;
        const u16* er = enc_b + ((size_t)s * Bn + b) * Hn + lane * 16;
        u16x8 e0 = *(const u16x8*)er, e1 = *(const u16x8*)(er + 8);
        float p = 0.f;
#pragma unroll
        for (int k2 = 0; k2 < 8; ++k2) p += bf2f(e0[k2]) * hf[k2] + bf2f(e1[k2]) * hf[8 + k2];
#pragma unroll
        for (int off = 32; off; off >>= 1) p += __shfl_xor(p, off);
        if (lane == 0) st_f32_coh(scores + b * Sn + s, p);
      }
      gbar(barcnt, (++bar) * NBLK);  // X end
      // phase Y: softmax + ctx quarter q for batch b
      if (wave == 0) {
        f32x2 sv = ld8_coh(scores + b * Sn + 2 * lane);
        float m = fmaxf(sv.x, sv.y);
#pragma unroll
        for (int off = 32; off; off >>= 1) m = fmaxf(m, __shfl_xor(m, off));
        float e0 = __expf(sv.x - m), e1 = __expf(sv.y - m);
        float d = e0 + e1;
#pragma unroll
        for (int off = 32; off; off >>= 1) d += __shfl_xor(d, off);
        float inv = 1.0f / d;
        wsm[2 * lane] = e0 * inv;
        wsm[2 * lane + 1] = e1 * inv;
      }
      __syncthreads();
      {
        int k = q * 256 + tid;
        const u16* ep = enc_b + (size_t)b * Hn + k;
        float a = 0.f;
        for (int s = 0; s < Sn; ++s) a += wsm[s] * bf2f(ep[(size_t)s * Bn * Hn]);
        u16 mine = f2bf(a);
        unsigned nb = (unsigned)(u16)__shfl_xor((int)mine, 1);
        if (!(tid & 1)) st32_coh(ctxb + (size_t)b * Hn + k, ((unsigned)mine) | (nb << 16));
      }
      asm volatile("s_waitcnt vmcnt(0)" ::: "memory");
      __syncthreads();
      if (tid == 0)
        __hip_atomic_fetch_add(cfine + ((b >> 4) * 4 + q) * 32, 1u, __ATOMIC_RELAXED,
                               __HIP_MEMORY_SCOPE_AGENT);
      gbar(barcnt, (++bar) * NBLK);  // Z end
    }
  }
}

// ---------------- host ----------------
extern "C" void kernel_launch(void* const* d_in, const int* in_sizes, int n_in,
                              void* d_out, int out_size, void* d_ws, size_t ws_size,
                              hipStream_t stream) {
  const int* src = (const int*)d_in[0];
  const int* tgt = (const int*)d_in[1];
  const float* embed = (const float*)d_in[2];
  const float* Wih0 = (const float*)d_in[3];
  const float* Whh0 = (const float*)d_in[4];
  const float* bih0 = (const float*)d_in[5];
  const float* bhh0 = (const float*)d_in[6];
  const float* Wih1 = (const float*)d_in[7];
  const float* Whh1 = (const float*)d_in[8];
  const float* bih1 = (const float*)d_in[9];
  const float* bhh1 = (const float*)d_in[10];
  const float* dWih = (const float*)d_in[11];
  const float* dWhh = (const float*)d_in[12];
  const float* dbih = (const float*)d_in[13];
  const float* dbhh = (const float*)d_in[14];
  const float* fcW = (const float*)d_in[15];
  const float* fcb = (const float*)d_in[16];
  float* out = (float*)d_out;

  char* p = (char*)d_ws;
  auto alloc = [&](size_t bytes) {
    void* r = p;
    p += (bytes + 255) & ~(size_t)255;
    return r;
  };
  u16* Wih0_b = (u16*)alloc((size_t)G4 * En * 2);
  u16* Whh0_b = (u16*)alloc((size_t)G4 * Hn * 2);
  u16* Wih1_b = (u16*)alloc((size_t)G4 * Hn * 2);
  u16* Whh1_b = (u16*)alloc((size_t)G4 * Hn * 2);
  u16* dWih_b = (u16*)alloc((size_t)G4 * 1536 * 2);
  u16* dWhh_b = (u16*)alloc((size_t)G4 * Hn * 2);
  u16* fcW_b = (u16*)alloc((size_t)Vn * Hn * 2);
  u16* embA = (u16*)alloc((size_t)4096 * En * 2);
  float* premix = (float*)alloc((size_t)4096 * G4 * 4);
  u16* enc_b = (u16*)alloc((size_t)Sn * Bn * Hn * 2);
  u16* hs_dec = (u16*)alloc((size_t)4096 * Hn * 2);
  u16* h0buf = (u16*)alloc((size_t)2 * Bn * Hn * 2);
  u16* h1buf = (u16*)alloc((size_t)2 * Bn * Hn * 2);
  float* c1g = (float*)alloc((size_t)Bn * Hn * 4);
  u16* ctx_b = (u16*)alloc((size_t)Bn * Hn * 2);
  float* scores = (float*)alloc((size_t)Bn * Sn * 4);
  unsigned* counters = (unsigned*)alloc(4096);
  unsigned* cnt_enc = counters;
  unsigned* cnt_dec = counters + 32;
  unsigned* cfine = counters + 64;  // 8 counters, stride 32 u32

  auto cvt = [&](const float* in, u16* o, size_t n) {
    int n8 = (int)(n / 8);
    cvt_bf16_kernel<<<(n8 + 255) / 256, 256, 0, stream>>>(in, o, n8);
  };
  cvt(Wih0, Wih0_b, (size_t)G4 * En);
  cvt(Whh0, Whh0_b, (size_t)G4 * Hn);
  cvt(Wih1, Wih1_b, (size_t)G4 * Hn);
  cvt(Whh1, Whh1_b, (size_t)G4 * Hn);
  cvt(dWih, dWih_b, (size_t)G4 * 1536);
  cvt(dWhh, dWhh_b, (size_t)G4 * Hn);
  cvt(fcW, fcW_b, (size_t)Vn * Hn);

  // encoder premix (layer0 input projection for all t)
  {
    int total = 4096 * (En / 8);
    gather_embed_kernel<<<(total + 255) / 256, 256, 0, stream>>>(src, Sn, embed, embA, Sn * Bn);
    gemm_tile_kernel<<<32 * 32, 256, 0, stream>>>(embA, En, Wih0_b, En, bih0, bhh0, premix, G4,
                                                  32, En, 0);
  }
  (void)hipMemsetAsync(h0buf, 0, (size_t)2 * Bn * Hn * 2, stream);
  (void)hipMemsetAsync(h1buf, 0, (size_t)2 * Bn * Hn * 2, stream);
  (void)hipMemsetAsync(counters, 0, 4096, stream);
  (void)hipMemsetAsync(hs_dec + (size_t)(Td * Bn) * Hn, 0, (size_t)(4096 - Td * Bn) * Hn * 2,
                       stream);

  enc_persist_kernel<<<NBLK, 256, 0, stream>>>(premix, Whh0_b, Wih1_b, Whh1_b, bih1, bhh1, h0buf,
                                               h1buf, c1g, enc_b, cnt_enc);

  // decoder premix
  {
    int nrows = Td * Bn;
    int total = nrows * (En / 8);
    gather_embed_kernel<<<(total + 255) / 256, 256, 0, stream>>>(tgt, Sn, embed, embA, nrows);
    gemm_tile_kernel<<<32 * 32, 256, 0, stream>>>(embA, En, dWih_b, 1536, dbih, dbhh, premix, G4,
                                                  32, En, 0);
  }

  dec_persist_kernel<<<NBLK, 256, 0, stream>>>(premix, dWih_b + 512, dWhh_b, c1g,
                                               h1buf /* = H1[0] = h_last */, enc_b, scores, ctx_b,
                                               hs_dec, cnt_dec, cfine);

  // batched fc: out = hs_dec @ fc_W^T + fc_b
  gemm_tile_kernel<<<32 * 250, 256, 0, stream>>>(hs_dec, Hn, fcW_b, Hn, fcb, nullptr, out, 0,
                                                 32, Hn, 1);
}

// Round 4
// 5256.430 us; speedup vs baseline: 1.4033x; 1.4033x over previous
//
#include <hip/hip_runtime.h>

// ---------------- types / helpers ----------------
typedef unsigned short u16;
typedef __bf16 bf16x8 __attribute__((ext_vector_type(8)));
typedef float f32x4 __attribute__((ext_vector_type(4)));
typedef u16 u16x8 __attribute__((ext_vector_type(8)));
typedef u16 u16x4v __attribute__((ext_vector_type(4)));
typedef unsigned u32x2 __attribute__((ext_vector_type(2)));

static_assert(sizeof(bf16x8) == 16, "bf16x8 must be 16B");

#define DEV static __device__ __forceinline__

DEV u16 f2bf(float f) {
  unsigned u = __float_as_uint(f);
  u += 0x7FFFu + ((u >> 16) & 1u);  // RNE
  return (u16)(u >> 16);
}
DEV float bf2f(u16 h) { return __uint_as_float(((unsigned)h) << 16); }
DEV f32x4 mfma16(bf16x8 a, bf16x8 b, f32x4 c) {
  return __builtin_amdgcn_mfma_f32_16x16x32_bf16(a, b, c, 0, 0, 0);
}
DEV bf16x8 ldfrag(const u16* p) { return *reinterpret_cast<const bf16x8*>(p); }
DEV float sigf(float x) { return 1.0f / (1.0f + __expf(-x)); }
DEV bf16x8 asbf(f32x4 v) { union { f32x4 f; bf16x8 h; } u; u.f = v; return u.h; }
DEV void gld16(const void* g, void* l) {
  __builtin_amdgcn_global_load_lds((const __attribute__((address_space(1))) void*)g,
                                   (__attribute__((address_space(3))) void*)l, 16, 0, 0);
}

// ---- coherent (MALL-level, cross-XCD) access helpers ----
DEV void ld_a8_coh(const void* p, f32x4& o0, f32x4& o1, f32x4& o2, f32x4& o3, f32x4& o4,
                   f32x4& o5, f32x4& o6, f32x4& o7) {
  asm volatile(
      "global_load_dwordx4 %0, %8, off sc0 sc1\n\t"
      "global_load_dwordx4 %1, %8, off offset:64 sc0 sc1\n\t"
      "global_load_dwordx4 %2, %8, off offset:128 sc0 sc1\n\t"
      "global_load_dwordx4 %3, %8, off offset:192 sc0 sc1\n\t"
      "global_load_dwordx4 %4, %8, off offset:256 sc0 sc1\n\t"
      "global_load_dwordx4 %5, %8, off offset:320 sc0 sc1\n\t"
      "global_load_dwordx4 %6, %8, off offset:384 sc0 sc1\n\t"
      "global_load_dwordx4 %7, %8, off offset:448 sc0 sc1\n\t"
      "s_waitcnt vmcnt(0)"
      : "=&v"(o0), "=&v"(o1), "=&v"(o2), "=&v"(o3), "=&v"(o4), "=&v"(o5), "=&v"(o6), "=&v"(o7)
      : "v"(p)
      : "memory");
}
DEV f32x4 ld16_coh(const void* p) {
  f32x4 r;
  asm volatile("global_load_dwordx4 %0, %1, off sc0 sc1\n\ts_waitcnt vmcnt(0)"
               : "=&v"(r) : "v"(p) : "memory");
  return r;
}
DEV void ld4f_coh(const void* p, float& a, float& b, float& c, float& d) {
  asm volatile(
      "global_load_dword %0, %4, off sc0 sc1\n\t"
      "global_load_dword %1, %4, off offset:32 sc0 sc1\n\t"
      "global_load_dword %2, %4, off offset:64 sc0 sc1\n\t"
      "global_load_dword %3, %4, off offset:96 sc0 sc1\n\t"
      "s_waitcnt vmcnt(0)"
      : "=&v"(a), "=&v"(b), "=&v"(c), "=&v"(d) : "v"(p) : "memory");
}
DEV void st32_coh(void* p, unsigned v) {
  asm volatile("global_store_dword %0, %1, off sc0 sc1" ::"v"(p), "v"(v) : "memory");
}
DEV void st_f32_coh(void* p, float v) {
  asm volatile("global_store_dword %0, %1, off sc0 sc1" ::"v"(p), "v"(v) : "memory");
}
DEV void st8_coh(void* p, unsigned lo, unsigned hi) {
  u32x2 v; v[0] = lo; v[1] = hi;
  asm volatile("global_store_dwordx2 %0, %1, off sc0 sc1" ::"v"(p), "v"(v) : "memory");
}

// ---- grid barrier: 2-level tree, monotonic counters, relaxed agent atomics ----
#define NBLK 256
DEV void gbar2(unsigned* leaf, unsigned* root, int blk, unsigned bar) {
  asm volatile("s_waitcnt vmcnt(0)" ::: "memory");
  __syncthreads();
  if (threadIdx.x == 0) {
    unsigned* lf = leaf + ((unsigned)blk >> 3) * 32;  // 32 groups of 8, 128B apart
    unsigned old = __hip_atomic_fetch_add(lf, 1u, __ATOMIC_RELAXED, __HIP_MEMORY_SCOPE_AGENT);
    if ((old & 7u) == 7u)
      __hip_atomic_fetch_add(root, 1u, __ATOMIC_RELAXED, __HIP_MEMORY_SCOPE_AGENT);
    while (__hip_atomic_load(root, __ATOMIC_RELAXED, __HIP_MEMORY_SCOPE_AGENT) < bar * 32u)
      __builtin_amdgcn_s_sleep(2);
  }
  __syncthreads();
}

// dims
#define Bn 32
#define Sn 128
#define Td 127
#define En 512
#define Hn 1024
#define G4 4096
#define Vn 32000

// ---------------- f32 -> bf16 convert ----------------
__global__ __launch_bounds__(256) void cvt_bf16_kernel(const float* __restrict__ in,
                                                       u16* __restrict__ out, int n8) {
  int gid = blockIdx.x * 256 + threadIdx.x;
  if (gid >= n8) return;
  const float4* ip = (const float4*)in + gid * 2;
  float4 x = ip[0], y = ip[1];
  u16x8 o;
  o[0] = f2bf(x.x); o[1] = f2bf(x.y); o[2] = f2bf(x.z); o[3] = f2bf(x.w);
  o[4] = f2bf(y.x); o[5] = f2bf(y.y); o[6] = f2bf(y.z); o[7] = f2bf(y.w);
  ((u16x8*)out)[gid] = o;
}

// ---------------- embedding gather ----------------
__global__ __launch_bounds__(256) void gather_embed_kernel(const int* __restrict__ idx, int ldidx,
                                                           const float* __restrict__ embed,
                                                           u16* __restrict__ outA, int nrows) {
  int gid = blockIdx.x * 256 + threadIdx.x;
  int total = nrows * (En / 8);
  if (gid >= total) return;
  int r = gid / (En / 8);
  int ck = gid % (En / 8);
  int tcol = r / Bn, b = r % Bn;
  int tok = idx[b * ldidx + tcol];
  const float4* src = (const float4*)(embed + (size_t)tok * En + ck * 8);
  float4 x = src[0], y = src[1];
  u16x8 o;
  o[0] = f2bf(x.x); o[1] = f2bf(x.y); o[2] = f2bf(x.z); o[3] = f2bf(x.w);
  o[4] = f2bf(y.x); o[5] = f2bf(y.y); o[6] = f2bf(y.z); o[7] = f2bf(y.w);
  *(u16x8*)(outA + (size_t)r * En + ck * 8) = o;
}

// ---------------- tiled GEMM (128x128, BK=32, global_load_lds) ----------------
__global__ __launch_bounds__(256) void gemm_tile_kernel(const u16* __restrict__ A, int lda,
                                                        const u16* __restrict__ W, int ldw,
                                                        const float* __restrict__ bias0,
                                                        const float* __restrict__ bias1,
                                                        float* __restrict__ Cout, int ldc,
                                                        int Mtiles, int K, int mode) {
  __shared__ u16 Asb[128 * 32];
  __shared__ u16 Bsb[128 * 32];
  int nwg = gridDim.x;
  int cpx = nwg >> 3;
  int bid = ((int)blockIdx.x & 7) * cpx + ((int)blockIdx.x >> 3);
  int mt = bid % Mtiles, nt = bid / Mtiles;
  int tid = threadIdx.x;
  int wave = tid >> 6, lane = tid & 63;
  int lrow = lane & 15, kgrp = lane >> 4;
  int wr = wave >> 1, wc = wave & 1;
  int e0 = wave * 1024 + lane * 8;
  int r0 = e0 >> 5, c0 = e0 & 31;
  int r1 = r0 + 16;
  const u16* Ab = A + (size_t)(mt * 128) * lda;
  const u16* Wb = W + (size_t)(nt * 128) * ldw;
  u16* AsW = Asb + wave * 1024;
  u16* BsW = Bsb + wave * 1024;
  f32x4 acc[4][4] = {};
  for (int k0 = 0; k0 < K; k0 += 32) {
    gld16(Ab + (size_t)r0 * lda + k0 + c0, AsW);
    gld16(Ab + (size_t)r1 * lda + k0 + c0, AsW + 512);
    gld16(Wb + (size_t)r0 * ldw + k0 + c0, BsW);
    gld16(Wb + (size_t)r1 * ldw + k0 + c0, BsW + 512);
    __syncthreads();
    bf16x8 af[4], bfr[4];
#pragma unroll
    for (int i = 0; i < 4; ++i) af[i] = ldfrag(Asb + (wr * 64 + i * 16 + lrow) * 32 + kgrp * 8);
#pragma unroll
    for (int i = 0; i < 4; ++i) bfr[i] = ldfrag(Bsb + (wc * 64 + i * 16 + lrow) * 32 + kgrp * 8);
#pragma unroll
    for (int i = 0; i < 4; ++i)
#pragma unroll
      for (int j = 0; j < 4; ++j) acc[i][j] = mfma16(af[i], bfr[j], acc[i][j]);
    __syncthreads();
  }
  if (mode == 0) {
#pragma unroll
    for (int i = 0; i < 4; ++i) {
      int m = mt * 128 + wr * 64 + i * 16 + kgrp * 4;
#pragma unroll
      for (int j = 0; j < 4; ++j) {
        int n = nt * 128 + wc * 64 + j * 16 + lrow;
        float bb = (bias0 ? bias0[n] : 0.f) + (bias1 ? bias1[n] : 0.f);
#pragma unroll
        for (int r = 0; r < 4; ++r) Cout[(size_t)(m + r) * ldc + n] = acc[i][j][r] + bb;
      }
    }
  } else {
#pragma unroll
    for (int i = 0; i < 4; ++i) {
      int m = mt * 128 + wr * 64 + i * 16 + kgrp * 4;
#pragma unroll
      for (int j = 0; j < 4; ++j) {
        int n = nt * 128 + wc * 64 + j * 16 + lrow;
        float bb = bias0[n];
#pragma unroll
        for (int r = 0; r < 4; ++r) {
          int mm = m + r;
          if (mm < Td * Bn) {
            int tt = mm >> 5, b = mm & 31;
            Cout[((size_t)b * Td + tt) * Vn + n] = acc[i][j][r] + bb;
          }
        }
      }
    }
  }
}

// ---------------- persistent building blocks ----------------
// 2Mx2N MFMA block: A (32x1024 bf16, coherent) slice vs LDS weights [32 cols][K], XOR-swizzled.
DEV void mm8(const u16* __restrict__ A0, const char* __restrict__ Wl, int pitchB,
             int kByteBase, int lane, f32x4 acc[2][2]) {
  const int lrow = lane & 15, kgrp = lane >> 4;
  const char* wr0 = Wl + (size_t)lrow * pitchB;
  const char* wr1 = wr0 + (size_t)16 * pitchB;
  const int sw = (lrow & 7) << 4;
#pragma unroll
  for (int m = 0; m < 2; ++m) {
    f32x4 t0, t1, t2, t3, t4, t5, t6, t7;
    ld_a8_coh(A0 + (size_t)(m * 16 + lrow) * 1024 + kgrp * 8, t0, t1, t2, t3, t4, t5, t6, t7);
#define KSX(T, J)                                                  \
    {                                                              \
      bf16x8 a = asbf(T);                                          \
      int kb = kByteBase + (J) * 64 + kgrp * 16;                   \
      bf16x8 b0 = *(const bf16x8*)(wr0 + (size_t)(kb ^ sw));       \
      bf16x8 b1 = *(const bf16x8*)(wr1 + (size_t)(kb ^ sw));       \
      acc[m][0] = mfma16(a, b0, acc[m][0]);                        \
      acc[m][1] = mfma16(a, b1, acc[m][1]);                        \
    }
    KSX(t0, 0) KSX(t1, 1) KSX(t2, 2) KSX(t3, 3)
    KSX(t4, 4) KSX(t5, 5) KSX(t6, 6) KSX(t7, 7)
#undef KSX
  }
}

DEV void dump_acc(float* red, f32x4 acc[2][2], int wave, int lane) {
  int lrow = lane & 15, kgrp = lane >> 4;
#pragma unroll
  for (int m = 0; m < 2; ++m)
#pragma unroll
    for (int n = 0; n < 2; ++n)
#pragma unroll
      for (int r = 0; r < 4; ++r)
        red[((((wave * 2 + m) * 2 + n) * 16) + kgrp * 4 + r) * 16 + lrow] = acc[m][n][r];
}
DEV float rsum(const float* red, int m, int n, int rw, int l) {
  float s = 0.f;
#pragma unroll
  for (int w = 0; w < 4; ++w) s += red[((((w * 2 + m) * 2 + n) * 16) + rw) * 16 + l];
  return s;
}
DEV float lstm_apply(const float gs[4], float* c_reg) {
  float ig = sigf(gs[0]), fg = sigf(gs[1]), gg = tanhf(gs[2]), og = sigf(gs[3]);
  float cn = fg * (*c_reg) + ig * gg;
  *c_reg = cn;
  return og * tanhf(cn);
}

// ---------------- persistent encoder (weights in LDS) ----------------
// blk<128: layer0, owns 8 h-cols, Whh0 slice 64KB in LDS.
// blk>=128: layer1, owns 8 h-cols, Wih1+Whh1 slices 128KB in LDS (K=2048 concat).
__global__ __launch_bounds__(256, 1) void enc_persist2(
    const float* __restrict__ premix, const u16* __restrict__ Whh0, const u16* __restrict__ Wih1,
    const u16* __restrict__ Whh1, const float* __restrict__ bih1, const float* __restrict__ bhh1,
    u16* __restrict__ h0buf, u16* __restrict__ h1buf, float* __restrict__ c1_out,
    u16* __restrict__ enc_b, unsigned* __restrict__ leaf, unsigned* __restrict__ root) {
  extern __shared__ char lds[];
  float* red = (float*)(lds + 131072);
  const int tid = threadIdx.x, wave = tid >> 6, lane = tid & 63;
  const int blk = blockIdx.x;
  const bool l1 = blk >= 128;
  const int base = (blk & 127) * 8;
  // ---- stage weights into LDS (once), XOR-swizzled ----
  if (!l1) {
    for (int i = tid; i < 4096; i += 256) {
      int c = i >> 7;
      int kb = (i & 127) << 4;
      int row = (c >> 3) * Hn + base + (c & 7);
      f32x4 v = *(const f32x4*)(Whh0 + (size_t)row * Hn + (kb >> 1));
      *(f32x4*)(lds + c * 2048 + (kb ^ ((c & 7) << 4))) = v;
    }
  } else {
    for (int i = tid; i < 8192; i += 256) {
      int c = i >> 8;
      int kb = (i & 255) << 4;
      int row = (c >> 3) * Hn + base + (c & 7);
      const u16* src = (kb < 2048) ? (Wih1 + (size_t)row * Hn + (kb >> 1))
                                   : (Whh1 + (size_t)row * Hn + ((kb - 2048) >> 1));
      f32x4 v = *(const f32x4*)src;
      *(f32x4*)(lds + c * 4096 + (kb ^ ((c & 7) << 4))) = v;
    }
  }
  const int b_ = tid >> 3, hc = tid & 7;
  float badd[4];
  if (l1) {
#pragma unroll
    for (int g = 0; g < 4; ++g) badd[g] = bih1[g * Hn + base + hc] + bhh1[g * Hn + base + hc];
  }
  __syncthreads();
  float c_reg = 0.f;
  for (int t = 0; t <= Sn; ++t) {
    bool active = l1 ? (t >= 1) : (t < Sn);
    if (active) {
      f32x4 acc[2][2] = {};
      if (!l1) {
        const u16* A = h0buf + (size_t)(t & 1) * (Bn * Hn);  // h0(t-1)
        mm8(A + wave * 256, lds, 2048, wave * 512, lane, acc);
      } else {
        const u16* h0r = h0buf + (size_t)(t & 1) * (Bn * Hn);        // h0(t-1)
        const u16* h1r = h1buf + (size_t)((t + 1) & 1) * (Bn * Hn);  // h1(t-2)
        const u16* src = (wave < 2) ? h0r : h1r;
        int ko = (wave & 1) * 512;
        mm8(src + ko, lds, 4096, wave * 1024, lane, acc);
        mm8(src + ko + 256, lds, 4096, wave * 1024 + 512, lane, acc);
      }
      dump_acc(red, acc, wave, lane);
      __syncthreads();
      int m = b_ >> 4, rw = b_ & 15;
      float gs[4];
#pragma unroll
      for (int g = 0; g < 4; ++g) {
        int c = g * 8 + hc;
        float s = rsum(red, m, c >> 4, rw, c & 15);
        if (!l1)
          s += premix[(size_t)t * (Bn * G4) + (size_t)b_ * G4 + g * Hn + base + hc];
        else
          s += badd[g];
        gs[g] = s;
      }
      float hn = lstm_apply(gs, &c_reg);
      u16 mine = f2bf(hn);
      unsigned nb = (unsigned)(u16)__shfl_xor((int)mine, 1);
      unsigned packed = ((unsigned)mine) | (nb << 16);
      size_t off = (size_t)b_ * Hn + base + hc;
      if (!l1) {
        if (!(tid & 1)) st32_coh(h0buf + (size_t)((t + 1) & 1) * (Bn * Hn) + off, packed);
      } else {
        if (!(tid & 1)) {
          st32_coh(h1buf + (size_t)(t & 1) * (Bn * Hn) + off, packed);
          *(unsigned*)(enc_b + (size_t)(t - 1) * (Bn * Hn) + off) = packed;
        }
        if (t == Sn) c1_out[off] = c_reg;
      }
    }
    gbar2(leaf, root, blk, (unsigned)(t + 1));
  }
}

// ---------------- persistent decoder (weights in LDS, 2 barriers/iter) ----------------
// blk<128 (role H): Whh K-part for 8 h-cols; writes f32 partials.
// blk>=128 (role C): Wctx K-part for same 8 h-cols; cg<32 also "scorer" (full attention for b=cg).
__global__ __launch_bounds__(256, 1) void dec_persist2(
    const float* __restrict__ premix, const u16* __restrict__ Wctx, const u16* __restrict__ Whh,
    const float* __restrict__ c_init, u16* __restrict__ hbuf, const u16* __restrict__ enc_b,
    u16* __restrict__ ctxb, float* __restrict__ Hpart, u16* __restrict__ hs_dec,
    unsigned* __restrict__ leaf, unsigned* __restrict__ root) {
  extern __shared__ char lds[];
  float* red = (float*)(lds + 65536);
  char* hsh = lds + 81920;          // 2 KB
  float* scl = (float*)(lds + 83968);  // 512 B
  float* wsm = (float*)(lds + 84480);  // 512 B
  const int tid = threadIdx.x, wave = tid >> 6, lane = tid & 63;
  const int blk = blockIdx.x;
  const bool rh = blk < 128;
  const int cg = rh ? blk : (blk - 128);
  const int base = cg * 8;
  // stage weights
  for (int i = tid; i < 4096; i += 256) {
    int c = i >> 7;
    int kb = (i & 127) << 4;
    int row = (c >> 3) * Hn + base + (c & 7);
    const u16* src = rh ? (Whh + (size_t)row * Hn + (kb >> 1))
                        : (Wctx + (size_t)row * 1536 + (kb >> 1));
    f32x4 v = *(const f32x4*)src;
    *(f32x4*)(lds + c * 2048 + (kb ^ ((c & 7) << 4))) = v;
  }
  const int b_ = tid >> 3, hc = tid & 7;
  float c_reg = 0.f;
  if (!rh) c_reg = c_init[(size_t)b_ * Hn + base + hc];
  __syncthreads();
  const bool scorer = (!rh) && (cg < 32);
  unsigned bar = 0;
  for (int t = 0; t < Td; ++t) {
    // ---------- P1: role-H h-GEMM  ||  scorers: full attention for batch b ----------
    if (rh) {
      f32x4 acc[2][2] = {};
      mm8(hbuf + wave * 256, lds, 2048, wave * 512, lane, acc);
      dump_acc(red, acc, wave, lane);
      __syncthreads();
      int m = b_ >> 4, rw = b_ & 15;
      float* hp = Hpart + (size_t)cg * 1024 + b_ * 32;
#pragma unroll
      for (int g = 0; g < 4; ++g) {
        int c = g * 8 + hc;
        st_f32_coh(hp + c, rsum(red, m, c >> 4, rw, c & 15));
      }
    } else if (scorer) {
      const int b = cg;
      if (tid < 128) {
        f32x4 v = ld16_coh(hbuf + (size_t)b * Hn + tid * 8);
        *(f32x4*)(hsh + tid * 16) = v;
      }
      __syncthreads();
      float hf[16];
      {
        const u16* hp = (const u16*)hsh + lane * 16;
#pragma unroll
        for (int q = 0; q < 16; ++q) hf[q] = bf2f(hp[q]);
      }
      for (int i = 0; i < 32; ++i) {
        int s = wave * 32 + i;
        const u16* er = enc_b + ((size_t)s * Bn + b) * Hn + lane * 16;
        u16x8 e0 = *(const u16x8*)er;
        u16x8 e1 = *(const u16x8*)(er + 8);
        float p = 0.f;
#pragma unroll
        for (int q = 0; q < 8; ++q) p += bf2f(e0[q]) * hf[q] + bf2f(e1[q]) * hf[8 + q];
#pragma unroll
        for (int off = 32; off; off >>= 1) p += __shfl_xor(p, off);
        if (lane == 0) scl[s] = p;
      }
      __syncthreads();
      if (wave == 0) {
        float a = scl[lane], b2 = scl[64 + lane];
        float mx = fmaxf(a, b2);
#pragma unroll
        for (int off = 32; off; off >>= 1) mx = fmaxf(mx, __shfl_xor(mx, off));
        float ea = __expf(a - mx), eb = __expf(b2 - mx);
        float ss = ea + eb;
#pragma unroll
        for (int off = 32; off; off >>= 1) ss += __shfl_xor(ss, off);
        float inv = 1.0f / ss;
        wsm[lane] = ea * inv;
        wsm[64 + lane] = eb * inv;
      }
      __syncthreads();
      float a4[4] = {0.f, 0.f, 0.f, 0.f};
      const u16* ep = enc_b + (size_t)b * Hn + tid * 4;
      for (int s = 0; s < Sn; ++s) {
        float w = wsm[s];
        u16x4v e = *(const u16x4v*)(ep + (size_t)s * (Bn * Hn));
        a4[0] += w * bf2f(e[0]);
        a4[1] += w * bf2f(e[1]);
        a4[2] += w * bf2f(e[2]);
        a4[3] += w * bf2f(e[3]);
      }
      unsigned lo = (unsigned)f2bf(a4[0]) | ((unsigned)f2bf(a4[1]) << 16);
      unsigned hi = (unsigned)f2bf(a4[2]) | ((unsigned)f2bf(a4[3]) << 16);
      st8_coh(ctxb + (size_t)b * Hn + tid * 4, lo, hi);
    }
    gbar2(leaf, root, blk, ++bar);
    // ---------- P2: role-C ctx-GEMM + partials + LSTM + publish h ----------
    if (!rh) {
      f32x4 acc[2][2] = {};
      mm8(ctxb + wave * 256, lds, 2048, wave * 512, lane, acc);
      dump_acc(red, acc, wave, lane);
      __syncthreads();
      int m = b_ >> 4, rw = b_ & 15;
      float g0, g1, g2, g3;
      ld4f_coh(Hpart + (size_t)cg * 1024 + b_ * 32 + hc, g0, g1, g2, g3);
      const float* pm = premix + (size_t)t * (Bn * G4) + (size_t)b_ * G4 + base + hc;
      float gs[4];
      float hadd[4] = {g0, g1, g2, g3};
#pragma unroll
      for (int g = 0; g < 4; ++g) {
        int c = g * 8 + hc;
        gs[g] = rsum(red, m, c >> 4, rw, c & 15) + hadd[g] + pm[(size_t)g * Hn];
      }
      float hn = lstm_apply(gs, &c_reg);
      u16 mine = f2bf(hn);
      unsigned nb = (unsigned)(u16)__shfl_xor((int)mine, 1);
      unsigned packed = ((unsigned)mine) | (nb << 16);
      size_t off = (size_t)b_ * Hn + base + hc;
      if (!(tid & 1)) {
        st32_coh(hbuf + off, packed);
        *(unsigned*)(hs_dec + (size_t)t * (Bn * Hn) + off) = packed;
      }
    }
    gbar2(leaf, root, blk, ++bar);
  }
}

// ---------------- host ----------------
extern "C" void kernel_launch(void* const* d_in, const int* in_sizes, int n_in,
                              void* d_out, int out_size, void* d_ws, size_t ws_size,
                              hipStream_t stream) {
  const int* src = (const int*)d_in[0];
  const int* tgt = (const int*)d_in[1];
  const float* embed = (const float*)d_in[2];
  const float* Wih0 = (const float*)d_in[3];
  const float* Whh0 = (const float*)d_in[4];
  const float* bih0 = (const float*)d_in[5];
  const float* bhh0 = (const float*)d_in[6];
  const float* Wih1 = (const float*)d_in[7];
  const float* Whh1 = (const float*)d_in[8];
  const float* bih1 = (const float*)d_in[9];
  const float* bhh1 = (const float*)d_in[10];
  const float* dWih = (const float*)d_in[11];
  const float* dWhh = (const float*)d_in[12];
  const float* dbih = (const float*)d_in[13];
  const float* dbhh = (const float*)d_in[14];
  const float* fcW = (const float*)d_in[15];
  const float* fcb = (const float*)d_in[16];
  float* out = (float*)d_out;

  (void)hipFuncSetAttribute((const void*)enc_persist2,
                            hipFuncAttributeMaxDynamicSharedMemorySize, 147456);
  (void)hipFuncSetAttribute((const void*)dec_persist2,
                            hipFuncAttributeMaxDynamicSharedMemorySize, 84992);

  char* p = (char*)d_ws;
  auto alloc = [&](size_t bytes) {
    void* r = p;
    p += (bytes + 255) & ~(size_t)255;
    return r;
  };
  u16* Wih0_b = (u16*)alloc((size_t)G4 * En * 2);
  u16* Whh0_b = (u16*)alloc((size_t)G4 * Hn * 2);
  u16* Wih1_b = (u16*)alloc((size_t)G4 * Hn * 2);
  u16* Whh1_b = (u16*)alloc((size_t)G4 * Hn * 2);
  u16* dWih_b = (u16*)alloc((size_t)G4 * 1536 * 2);
  u16* dWhh_b = (u16*)alloc((size_t)G4 * Hn * 2);
  u16* fcW_b = (u16*)alloc((size_t)Vn * Hn * 2);
  u16* embA = (u16*)alloc((size_t)4096 * En * 2);
  float* premix = (float*)alloc((size_t)4096 * G4 * 4);  // reused: enc l0, then decoder
  u16* enc_b = (u16*)alloc((size_t)Sn * Bn * Hn * 2);
  u16* hs_dec = (u16*)alloc((size_t)4096 * Hn * 2);
  u16* h0buf = (u16*)alloc((size_t)2 * Bn * Hn * 2);
  u16* h1buf = (u16*)alloc((size_t)2 * Bn * Hn * 2);
  float* c1g = (float*)alloc((size_t)Bn * Hn * 4);
  u16* ctx_b = (u16*)alloc((size_t)Bn * Hn * 2);
  float* Hpart = (float*)alloc((size_t)128 * 1024 * 4);
  unsigned* counters = (unsigned*)alloc(16384);
  unsigned* leafE = counters;          // 32 x 32 u32
  unsigned* leafD = counters + 1024;   // 32 x 32 u32
  unsigned* rootE = counters + 2048;
  unsigned* rootD = counters + 2080;

  auto cvt = [&](const float* in, u16* o, size_t n) {
    int n8 = (int)(n / 8);
    cvt_bf16_kernel<<<(n8 + 255) / 256, 256, 0, stream>>>(in, o, n8);
  };
  cvt(Wih0, Wih0_b, (size_t)G4 * En);
  cvt(Whh0, Whh0_b, (size_t)G4 * Hn);
  cvt(Wih1, Wih1_b, (size_t)G4 * Hn);
  cvt(Whh1, Whh1_b, (size_t)G4 * Hn);
  cvt(dWih, dWih_b, (size_t)G4 * 1536);
  cvt(dWhh, dWhh_b, (size_t)G4 * Hn);
  cvt(fcW, fcW_b, (size_t)Vn * Hn);

  // encoder premix (layer0 input projection for all t)
  {
    int total = 4096 * (En / 8);
    gather_embed_kernel<<<(total + 255) / 256, 256, 0, stream>>>(src, Sn, embed, embA, Sn * Bn);
    gemm_tile_kernel<<<32 * 32, 256, 0, stream>>>(embA, En, Wih0_b, En, bih0, bhh0, premix, G4,
                                                  32, En, 0);
  }
  (void)hipMemsetAsync(h0buf, 0, (size_t)2 * Bn * Hn * 2, stream);
  (void)hipMemsetAsync(h1buf, 0, (size_t)2 * Bn * Hn * 2, stream);
  (void)hipMemsetAsync(counters, 0, 16384, stream);
  (void)hipMemsetAsync(hs_dec + (size_t)(Td * Bn) * Hn, 0, (size_t)(4096 - Td * Bn) * Hn * 2,
                       stream);

  enc_persist2<<<NBLK, 256, 147456, stream>>>(premix, Whh0_b, Wih1_b, Whh1_b, bih1, bhh1, h0buf,
                                              h1buf, c1g, enc_b, leafE, rootE);

  // decoder premix
  {
    int nrows = Td * Bn;
    int total = nrows * (En / 8);
    gather_embed_kernel<<<(total + 255) / 256, 256, 0, stream>>>(tgt, Sn, embed, embA, nrows);
    gemm_tile_kernel<<<32 * 32, 256, 0, stream>>>(embA, En, dWih_b, 1536, dbih, dbhh, premix, G4,
                                                  32, En, 0);
  }

  dec_persist2<<<NBLK, 256, 84992, stream>>>(premix, dWih_b + 512, dWhh_b, c1g,
                                             h1buf /* slot0 = h_last */, enc_b, ctx_b, Hpart,
                                             hs_dec, leafD, rootD);

  // batched fc: out = hs_dec @ fc_W^T + fc_b
  gemm_tile_kernel<<<32 * 250, 256, 0, stream>>>(hs_dec, Hn, fcW_b, Hn, fcb, nullptr, out, 0,
                                                 32, Hn, 1);
}